// Round 9
// baseline (861.434 us; speedup 1.0000x reference)
//
#include <hip/hip_runtime.h>
#include <hip/hip_bf16.h>
#include <math.h>
#include <stdint.h>

#define NN 50000
#define NE 400000

typedef __attribute__((ext_vector_type(8))) short short8;
typedef __attribute__((ext_vector_type(4))) float f32x4;

// bf16 weight workspace layout (element offsets)
#define OFF_W1S  0           // [128][128]  We1 rows 0..127   (src half), transposed
#define OFF_W1D  16384       // [128][128]  We1 rows 128..255 (dst half)
#define OFF_W1E  32768       // [128][64]   We1 rows 256..319 (edge_attr part)
#define OFF_WE2T 40960       // [128][128]
#define OFF_WN1T 57344       // [128][256]
#define OFF_WN2T 90112       // [128][128]
#define OFF_WC1T 106496      // [64][128]
#define W_TOTAL  114688

__device__ __forceinline__ float silu_f(float x) {
    return x * (1.0f / (1.0f + __expf(-x)));
}
__device__ __forceinline__ short f2bf(float f) {
    __hip_bfloat16 b = __float2bfloat16(f);
    return *reinterpret_cast<short*>(&b);
}
__device__ __forceinline__ float bf2f(short s) {
    uint32_t u = ((uint32_t)(uint16_t)s) << 16;
    float f; __builtin_memcpy(&f, &u, 4); return f;
}
__device__ __forceinline__ uint32_t pk2(float lo, float hi) {
    return (uint32_t)(uint16_t)f2bf(lo) | ((uint32_t)(uint16_t)f2bf(hi) << 16);
}
__device__ __forceinline__ short8 cvt8(float4 a, float4 b) {
    short8 r;
    r[0] = f2bf(a.x); r[1] = f2bf(a.y); r[2] = f2bf(a.z); r[3] = f2bf(a.w);
    r[4] = f2bf(b.x); r[5] = f2bf(b.y); r[6] = f2bf(b.z); r[7] = f2bf(b.w);
    return r;
}

// C-pack -> B-fragment lane exchange (proven R4/R5). e0/e1 = col-tile 2cc packs,
// o0/o1 = col-tile 2cc+1 packs; returns this lane's B-frag short8 (cols g*8..+7).
__device__ __forceinline__ short8 exch8(uint32_t e0, uint32_t e1,
                                        uint32_t o0, uint32_t o1,
                                        int g, int le) {
    const int srcA = le + 16 * ((g & 1) * 2);
    const int srcB = srcA + 16;
    const uint32_t a0e = __shfl((int)e0, srcA), a0o = __shfl((int)o0, srcA);
    const uint32_t a1e = __shfl((int)e1, srcA), a1o = __shfl((int)o1, srcA);
    const uint32_t b0e = __shfl((int)e0, srcB), b0o = __shfl((int)o0, srcB);
    const uint32_t b1e = __shfl((int)e1, srcB), b1o = __shfl((int)o1, srcB);
    const bool hi = (g & 2) != 0;
    uint32_t v[4];
    v[0] = hi ? a0o : a0e;  v[1] = hi ? a1o : a1e;
    v[2] = hi ? b0o : b0e;  v[3] = hi ? b1o : b1e;
    short8 r; __builtin_memcpy(&r, v, 16); return r;
}

// ---------------- zero aggr/coord accumulators ----------------
__global__ void zero_kernel(float4* __restrict__ p, int n4) {
    int i = blockIdx.x * blockDim.x + threadIdx.x;
    int st = gridDim.x * blockDim.x;
    for (; i < n4; i += st) p[i] = make_float4(0.f, 0.f, 0.f, 0.f);
}

// ---------------- prep: weights fp32 [K][N] -> bf16 transposed [N][K] ----------------
__global__ __launch_bounds__(256) void prep_kernel(
    const float* __restrict__ We1, const float* __restrict__ We2,
    const float* __restrict__ Wn1, const float* __restrict__ Wn2,
    const float* __restrict__ Wc1, short* __restrict__ wb)
{
    const int i = blockIdx.x * 256 + threadIdx.x;
    if (i >= W_TOTAL) return;
    float v; int rel, n, k;
    if (i < OFF_W1D)       { rel = i;            n = rel >> 7; k = rel & 127; v = We1[k * 128 + n]; }
    else if (i < OFF_W1E)  { rel = i - OFF_W1D;  n = rel >> 7; k = rel & 127; v = We1[(k + 128) * 128 + n]; }
    else if (i < OFF_WE2T) { rel = i - OFF_W1E;  n = rel >> 6; k = rel & 63;  v = We1[(k + 256) * 128 + n]; }
    else if (i < OFF_WN1T) { rel = i - OFF_WE2T; n = rel >> 7; k = rel & 127; v = We2[k * 128 + n]; }
    else if (i < OFF_WN2T) { rel = i - OFF_WN1T; n = rel >> 8; k = rel & 255; v = Wn1[k * 128 + n]; }
    else if (i < OFF_WC1T) { rel = i - OFF_WN2T; n = rel >> 7; k = rel & 127; v = Wn2[k * 128 + n]; }
    else                   { rel = i - OFF_WC1T; n = rel >> 7; k = rel & 127; v = Wc1[k * 64 + n]; }
    wb[i] = f2bf(v);
}

// ---------------- ynode: Ys = nf @ We1_src, Yd = nf @ We1_dst (bf16 out) ----------------
__global__ __launch_bounds__(256, 4) void ynode_kernel(
    const float* __restrict__ nf, const short* __restrict__ wb,
    short* __restrict__ ysb, short* __restrict__ ydb)
{
    const int tid = threadIdx.x;
    const int wv = tid >> 6, lane = tid & 63, le = lane & 15, grp = lane >> 4;
    const int nb = blockIdx.x * 128, wbase = wv * 32;
    const int row0 = min(nb + wbase + le, NN - 1);
    const int row1 = min(nb + wbase + 16 + le, NN - 1);

    #pragma unroll 1
    for (int pass = 0; pass < 2; ++pass) {
        const short* wt = wb + (pass ? OFF_W1D : OFF_W1S);
        short* op = pass ? ydb : ysb;

        f32x4 acc[2][8];
        #pragma unroll
        for (int m = 0; m < 2; ++m)
            #pragma unroll
            for (int t = 0; t < 8; ++t) acc[m][t] = (f32x4){0.f, 0.f, 0.f, 0.f};

        #pragma unroll
        for (int kc = 0; kc < 4; ++kc) {
            const int gk = kc * 32 + grp * 8;
            const float* p0 = nf + (size_t)row0 * 128 + gk;
            const float* p1 = nf + (size_t)row1 * 128 + gk;
            const short8 a0 = cvt8(*(const float4*)p0, *(const float4*)(p0 + 4));
            const short8 a1 = cvt8(*(const float4*)p1, *(const float4*)(p1 + 4));
            short8 bfv[8];
            #pragma unroll
            for (int t = 0; t < 8; ++t)
                bfv[t] = *(const short8*)(wt + (size_t)(t * 16 + le) * 128 + gk);
            #pragma unroll
            for (int t = 0; t < 8; ++t) {
                acc[0][t] = __builtin_amdgcn_mfma_f32_16x16x32_bf16(a0, bfv[t], acc[0][t], 0, 0, 0);
                acc[1][t] = __builtin_amdgcn_mfma_f32_16x16x32_bf16(a1, bfv[t], acc[1][t], 0, 0, 0);
            }
        }
        #pragma unroll
        for (int t = 0; t < 8; ++t)
            #pragma unroll
            for (int m = 0; m < 2; ++m)
                #pragma unroll
                for (int r = 0; r < 4; ++r) {
                    const int row = nb + wbase + m * 16 + grp * 4 + r;
                    if (row < NN)
                        op[(size_t)row * 128 + t * 16 + le] = f2bf(acc[m][t][r]);
                }
    }
}

// ---------------- edge pipeline: ZERO LDS, swapped GEMMs, register gathers ----------------
// 64 edges/block, 4 waves, 16 edges/wave. Lane le owns edge base+le entirely:
// s0/d0 in registers -> Ys[s0]/Yd[d0] gathered straight into B-fragment registers.
// C->B transposes via exch8 shuffles. No __shared__, no barriers -> occupancy
// capped only by VGPR (target 4 waves/SIMD).
__global__ __launch_bounds__(256, 4) void edge_kernel(
    const short* __restrict__ ysb, const short* __restrict__ ydb,
    const float* __restrict__ ea, const float* __restrict__ coords,
    const int* __restrict__ ei, const short* __restrict__ wb,
    const float* __restrict__ be1, const float* __restrict__ be2,
    const float* __restrict__ bc1, const float* __restrict__ bc2,
    const float* __restrict__ Wc2f,
    float* __restrict__ aggr, float* __restrict__ coord_acc)
{
    const int tid = threadIdx.x;
    const int wv = tid >> 6, lane = tid & 63, le = lane & 15, g = lane >> 4;
    const int e = (blockIdx.x * 4 + wv) * 16 + le;

    const int s0 = ei[e], d0 = ei[NE + e];

    // register gathers: Ys[s0], Yd[d0] as B-frag chunks (cc=0..3), 16B per load
    short8 ys8[4], yd8[4];
    #pragma unroll
    for (int cc = 0; cc < 4; ++cc) {
        ys8[cc] = *(const short8*)(ysb + (size_t)s0 * 128 + cc * 32 + g * 8);
        yd8[cc] = *(const short8*)(ydb + (size_t)d0 * 128 + cc * 32 + g * 8);
    }

    // edge_attr B-frags (coalesced fp32 stream)
    short8 eaB[2];
    #pragma unroll
    for (int kc = 0; kc < 2; ++kc) {
        const float* pe = ea + (size_t)e * 64 + kc * 32 + g * 8;
        eaB[kc] = cvt8(*(const float4*)pe, *(const float4*)(pe + 4));
    }

    // ===== MLP1 ea-part (swapped): acc[t] = (W1E^T ea^T), C: lane le = edge, col t*16+g*4+r
    f32x4 acc[8];
    #pragma unroll
    for (int t = 0; t < 8; ++t) acc[t] = (f32x4){0.f, 0.f, 0.f, 0.f};

    const short* w1e = wb + OFF_W1E;
    #pragma unroll
    for (int kc = 0; kc < 2; ++kc) {
        const int gk = kc * 32 + g * 8;
        short8 wfv[8];
        #pragma unroll
        for (int t = 0; t < 8; ++t)
            wfv[t] = *(const short8*)(w1e + (size_t)(t * 16 + le) * 64 + gk);
        #pragma unroll
        for (int t = 0; t < 8; ++t)
            acc[t] = __builtin_amdgcn_mfma_f32_16x16x32_bf16(wfv[t], eaB[kc], acc[t], 0, 0, 0);
    }

    // pack ea-part C-frags to bf16 pairs
    uint32_t hp[8][2];
    #pragma unroll
    for (int t = 0; t < 8; ++t) {
        hp[t][0] = pk2(acc[t][0], acc[t][1]);
        hp[t][1] = pk2(acc[t][2], acc[t][3]);
    }

    // ===== h1 B-frags: exch(ea-part) + Ys + Yd + be1, silu — all in registers
    short8 h1f[4];
    #pragma unroll
    for (int cc = 0; cc < 4; ++cc) {
        const short8 ex = exch8(hp[cc*2][0], hp[cc*2][1], hp[cc*2+1][0], hp[cc*2+1][1], g, le);
        const float* bp = be1 + cc * 32 + g * 8;
        #pragma unroll
        for (int j = 0; j < 8; ++j)
            h1f[cc][j] = f2bf(silu_f(bf2f(ex[j]) + bf2f(ys8[cc][j]) + bf2f(yd8[cc][j]) + bp[j]));
    }

    // ===== MLP2 (swapped): acc2[t], K=128
    f32x4 acc2[8];
    #pragma unroll
    for (int t = 0; t < 8; ++t) acc2[t] = (f32x4){0.f, 0.f, 0.f, 0.f};

    const short* w2 = wb + OFF_WE2T;
    #pragma unroll
    for (int cc = 0; cc < 4; ++cc) {
        const int gk = cc * 32 + g * 8;
        short8 wfv[8];
        #pragma unroll
        for (int t = 0; t < 8; ++t)
            wfv[t] = *(const short8*)(w2 + (size_t)(t * 16 + le) * 128 + gk);
        #pragma unroll
        for (int t = 0; t < 8; ++t)
            acc2[t] = __builtin_amdgcn_mfma_f32_16x16x32_bf16(wfv[t], h1f[cc], acc2[t], 0, 0, 0);
    }

    // ===== h2: bias+silu, atomic scatter to own d0, pack for exch
    uint32_t hq[8][2];
    #pragma unroll
    for (int t = 0; t < 8; ++t) {
        float hv[4];
        #pragma unroll
        for (int r = 0; r < 4; ++r) {
            const int col = t * 16 + g * 4 + r;
            const float v = silu_f(acc2[t][r] + be2[col]);
            hv[r] = v;
            atomicAdd(&aggr[(size_t)d0 * 128 + col], v);
        }
        hq[t][0] = pk2(hv[0], hv[1]);
        hq[t][1] = pk2(hv[2], hv[3]);
    }

    // h2 B-frags via exch
    short8 h2f[4];
    #pragma unroll
    for (int cc = 0; cc < 4; ++cc)
        h2f[cc] = exch8(hq[cc*2][0], hq[cc*2][1], hq[cc*2+1][0], hq[cc*2+1][1], g, le);

    // ===== coord MLP (swapped), N=64: acc3[t=0..3]
    f32x4 acc3[4];
    #pragma unroll
    for (int t = 0; t < 4; ++t) acc3[t] = (f32x4){0.f, 0.f, 0.f, 0.f};

    const short* wc = wb + OFF_WC1T;
    #pragma unroll
    for (int cc = 0; cc < 4; ++cc) {
        const int gk = cc * 32 + g * 8;
        short8 wfv[4];
        #pragma unroll
        for (int t = 0; t < 4; ++t)
            wfv[t] = *(const short8*)(wc + (size_t)(t * 16 + le) * 128 + gk);
        #pragma unroll
        for (int t = 0; t < 4; ++t)
            acc3[t] = __builtin_amdgcn_mfma_f32_16x16x32_bf16(wfv[t], h2f[cc], acc3[t], 0, 0, 0);
    }

    // coord_w: per-lane partial over cols, reduce across the 4 g-lanes of this edge
    float part = 0.f;
    #pragma unroll
    for (int t = 0; t < 4; ++t)
        #pragma unroll
        for (int r = 0; r < 4; ++r) {
            const int col = t * 16 + g * 4 + r;
            part += silu_f(acc3[t][r] + bc1[col]) * Wc2f[col];
        }
    part += __shfl_xor(part, 16);
    part += __shfl_xor(part, 32);

    if (g == 0) {
        const float wq = part + bc2[0];
        const float dx = coords[3 * s0 + 0] - coords[3 * d0 + 0];
        const float dy = coords[3 * s0 + 1] - coords[3 * d0 + 1];
        const float dz = coords[3 * s0 + 2] - coords[3 * d0 + 2];
        const float inv = wq / (sqrtf(dx * dx + dy * dy + dz * dz) + 1e-8f);
        atomicAdd(&coord_acc[3 * d0 + 0], dx * inv);
        atomicAdd(&coord_acc[3 * d0 + 1], dy * inv);
        atomicAdd(&coord_acc[3 * d0 + 2], dz * inv);
    }
}

// ---------------- node update (MFMA, barrier-free, fp32 inputs) ----------------
__global__ __launch_bounds__(256, 2) void node_kernel(
    const float* __restrict__ nf, const float* __restrict__ coords,
    const short* __restrict__ wb,
    const float* __restrict__ bn1, const float* __restrict__ bn2,
    const float* __restrict__ aggr, const float* __restrict__ coord_acc,
    float* __restrict__ out)
{
    __shared__ short Hs[128][136];

    const int tid = threadIdx.x;
    const int wv = tid >> 6, lane = tid & 63, le = lane & 15, grp = lane >> 4;
    const int nb = blockIdx.x * 128, wbase = wv * 32;
    const int row0 = min(nb + wbase + le, NN - 1);
    const int row1 = min(nb + wbase + 16 + le, NN - 1);

    // MLP1: K=256 ([nf | aggr])
    f32x4 acc[2][8];
    #pragma unroll
    for (int m = 0; m < 2; ++m)
        #pragma unroll
        for (int t = 0; t < 8; ++t) acc[m][t] = (f32x4){0.f, 0.f, 0.f, 0.f};

    const short* w1 = wb + OFF_WN1T;
    #pragma unroll
    for (int kc = 0; kc < 8; ++kc) {
        const int gk = kc * 32 + grp * 8;
        const float* p0 = (kc < 4) ? nf + (size_t)row0 * 128 + gk : aggr + (size_t)row0 * 128 + gk - 128;
        const float* p1 = (kc < 4) ? nf + (size_t)row1 * 128 + gk : aggr + (size_t)row1 * 128 + gk - 128;
        const short8 a0 = cvt8(*(const float4*)p0, *(const float4*)(p0 + 4));
        const short8 a1 = cvt8(*(const float4*)p1, *(const float4*)(p1 + 4));
        short8 bfv[8];
        #pragma unroll
        for (int t = 0; t < 8; ++t)
            bfv[t] = *(const short8*)(w1 + (size_t)(t * 16 + le) * 256 + gk);
        #pragma unroll
        for (int t = 0; t < 8; ++t) {
            acc[0][t] = __builtin_amdgcn_mfma_f32_16x16x32_bf16(a0, bfv[t], acc[0][t], 0, 0, 0);
            acc[1][t] = __builtin_amdgcn_mfma_f32_16x16x32_bf16(a1, bfv[t], acc[1][t], 0, 0, 0);
        }
    }
    #pragma unroll
    for (int t = 0; t < 8; ++t) {
        const float b1 = bn1[t * 16 + le];
        #pragma unroll
        for (int m = 0; m < 2; ++m)
            #pragma unroll
            for (int r = 0; r < 4; ++r)
                Hs[wbase + m * 16 + grp * 4 + r][t * 16 + le] = f2bf(silu_f(acc[m][t][r] + b1));
    }

    // MLP2: K=128, then residual
    f32x4 acc2[2][8];
    #pragma unroll
    for (int m = 0; m < 2; ++m)
        #pragma unroll
        for (int t = 0; t < 8; ++t) acc2[m][t] = (f32x4){0.f, 0.f, 0.f, 0.f};

    const short* w2 = wb + OFF_WN2T;
    #pragma unroll
    for (int kc = 0; kc < 4; ++kc) {
        const int gk = kc * 32 + grp * 8;
        const short8 a0 = *(const short8*)&Hs[wbase + le][gk];
        const short8 a1 = *(const short8*)&Hs[wbase + 16 + le][gk];
        short8 bfv[8];
        #pragma unroll
        for (int t = 0; t < 8; ++t)
            bfv[t] = *(const short8*)(w2 + (size_t)(t * 16 + le) * 128 + gk);
        #pragma unroll
        for (int t = 0; t < 8; ++t) {
            acc2[0][t] = __builtin_amdgcn_mfma_f32_16x16x32_bf16(a0, bfv[t], acc2[0][t], 0, 0, 0);
            acc2[1][t] = __builtin_amdgcn_mfma_f32_16x16x32_bf16(a1, bfv[t], acc2[1][t], 0, 0, 0);
        }
    }
    #pragma unroll
    for (int t = 0; t < 8; ++t) {
        const float b2 = bn2[t * 16 + le];
        #pragma unroll
        for (int m = 0; m < 2; ++m)
            #pragma unroll
            for (int r = 0; r < 4; ++r) {
                const int row = nb + wbase + m * 16 + grp * 4 + r;
                if (row < NN) {
                    const int c = t * 16 + le;
                    out[(size_t)row * 128 + c] = acc2[m][t][r] + b2 + nf[(size_t)row * 128 + c];
                }
            }
    }

    // coords epilogue
    for (int i = tid; i < 384; i += 256) {
        const int n = nb + i / 3, j = i % 3;
        if (n < NN)
            out[(size_t)NN * 128 + 3 * n + j] = coords[3 * n + j] + coord_acc[3 * n + j];
    }
}

extern "C" void kernel_launch(void* const* d_in, const int* in_sizes, int n_in,
                              void* d_out, int out_size, void* d_ws, size_t ws_size,
                              hipStream_t stream)
{
    const float* node_feat  = (const float*)d_in[0];
    const float* edge_attr  = (const float*)d_in[1];
    const float* coords     = (const float*)d_in[2];
    const int*   edge_index = (const int*)d_in[3];
    const float* We1 = (const float*)d_in[4];
    const float* be1 = (const float*)d_in[5];
    const float* We2 = (const float*)d_in[6];
    const float* be2 = (const float*)d_in[7];
    const float* Wn1 = (const float*)d_in[8];
    const float* bn1 = (const float*)d_in[9];
    const float* Wn2 = (const float*)d_in[10];
    const float* bn2 = (const float*)d_in[11];
    const float* Wc1 = (const float*)d_in[12];
    const float* bc1 = (const float*)d_in[13];
    const float* Wc2 = (const float*)d_in[14];
    const float* bc2 = (const float*)d_in[15];
    float* out = (float*)d_out;

    const size_t sz_wb  = (size_t)W_TOTAL * 2;      // 229 KB
    const size_t sz_agg = (size_t)NN * 128 * 4;     // 25.6 MB
    const size_t sz_cac = (size_t)NN * 3 * 4;       // 600 KB
    const size_t sz_y   = (size_t)NN * 128 * 2;     // 12.8 MB each

    char* p = (char*)d_ws;
    short* wbf       = (short*)p;  p += sz_wb;
    float* aggr      = (float*)p;  p += sz_agg;
    float* coord_acc = (float*)p;  p += sz_cac;
    short* ysb       = (short*)p;  p += sz_y;
    short* ydb       = (short*)p;
    (void)ws_size;

    const int n4 = (NN * 128 + NN * 3) / 4;
    const int eg = NE / 64;                   // 6250 blocks (4 waves x 16 edges)
    const int ng = (NN + 127) / 128;          // 391

    prep_kernel<<<(W_TOTAL + 255) / 256, 256, 0, stream>>>(We1, We2, Wn1, Wn2, Wc1, wbf);
    zero_kernel<<<2048, 256, 0, stream>>>((float4*)aggr, n4);
    ynode_kernel<<<ng, 256, 0, stream>>>(node_feat, wbf, ysb, ydb);

    edge_kernel<<<eg, 256, 0, stream>>>(
        ysb, ydb, edge_attr, coords, edge_index, wbf,
        be1, be2, bc1, bc2, Wc2, aggr, coord_acc);

    node_kernel<<<ng, 256, 0, stream>>>(
        node_feat, coords, wbf, bn1, bn2, aggr, coord_acc, out);
}

// Round 10
// 389.964 us; speedup vs baseline: 2.2090x; 2.2090x over previous
//
#include <hip/hip_runtime.h>
#include <hip/hip_bf16.h>
#include <math.h>
#include <stdint.h>

#define NN 50000
#define NE 400000

typedef __attribute__((ext_vector_type(8))) short short8;
typedef __attribute__((ext_vector_type(4))) float f32x4;

// bf16 weight workspace layout (element offsets)
#define OFF_W1S  0           // [128][128]  We1 rows 0..127   (src half), transposed
#define OFF_W1D  16384       // [128][128]  We1 rows 128..255 (dst half)
#define OFF_W1E  32768       // [128][64]   We1 rows 256..319 (edge_attr part)
#define OFF_WE2T 40960       // [128][128]
#define OFF_WN1T 57344       // [128][256]
#define OFF_WN2T 90112       // [128][128]
#define OFF_WC1T 106496      // [64][128]
#define W_TOTAL  114688

__device__ __forceinline__ float silu_f(float x) {
    return x * (1.0f / (1.0f + __expf(-x)));
}
__device__ __forceinline__ short f2bf(float f) {
    __hip_bfloat16 b = __float2bfloat16(f);
    return *reinterpret_cast<short*>(&b);
}
__device__ __forceinline__ float bf2f(short s) {
    uint32_t u = ((uint32_t)(uint16_t)s) << 16;
    float f; __builtin_memcpy(&f, &u, 4); return f;
}
__device__ __forceinline__ uint32_t pk2(float lo, float hi) {
    return (uint32_t)(uint16_t)f2bf(lo) | ((uint32_t)(uint16_t)f2bf(hi) << 16);
}
__device__ __forceinline__ short8 cvt8(float4 a, float4 b) {
    short8 r;
    r[0] = f2bf(a.x); r[1] = f2bf(a.y); r[2] = f2bf(a.z); r[3] = f2bf(a.w);
    r[4] = f2bf(b.x); r[5] = f2bf(b.y); r[6] = f2bf(b.z); r[7] = f2bf(b.w);
    return r;
}

// C-pack -> B-fragment lane exchange (proven R4/R5/R9).
__device__ __forceinline__ short8 exch8(uint32_t e0, uint32_t e1,
                                        uint32_t o0, uint32_t o1,
                                        int g, int le) {
    const int srcA = le + 16 * ((g & 1) * 2);
    const int srcB = srcA + 16;
    const uint32_t a0e = __shfl((int)e0, srcA), a0o = __shfl((int)o0, srcA);
    const uint32_t a1e = __shfl((int)e1, srcA), a1o = __shfl((int)o1, srcA);
    const uint32_t b0e = __shfl((int)e0, srcB), b0o = __shfl((int)o0, srcB);
    const uint32_t b1e = __shfl((int)e1, srcB), b1o = __shfl((int)o1, srcB);
    const bool hi = (g & 2) != 0;
    uint32_t v[4];
    v[0] = hi ? a0o : a0e;  v[1] = hi ? a1o : a1e;
    v[2] = hi ? b0o : b0e;  v[3] = hi ? b1o : b1e;
    short8 r; __builtin_memcpy(&r, v, 16); return r;
}

// ---------------- zero aggr/coord accumulators ----------------
__global__ void zero_kernel(float4* __restrict__ p, int n4) {
    int i = blockIdx.x * blockDim.x + threadIdx.x;
    int st = gridDim.x * blockDim.x;
    for (; i < n4; i += st) p[i] = make_float4(0.f, 0.f, 0.f, 0.f);
}

// ---------------- prep: weights fp32 [K][N] -> bf16 transposed [N][K] ----------------
__global__ __launch_bounds__(256) void prep_kernel(
    const float* __restrict__ We1, const float* __restrict__ We2,
    const float* __restrict__ Wn1, const float* __restrict__ Wn2,
    const float* __restrict__ Wc1, short* __restrict__ wb)
{
    const int i = blockIdx.x * 256 + threadIdx.x;
    if (i >= W_TOTAL) return;
    float v; int rel, n, k;
    if (i < OFF_W1D)       { rel = i;            n = rel >> 7; k = rel & 127; v = We1[k * 128 + n]; }
    else if (i < OFF_W1E)  { rel = i - OFF_W1D;  n = rel >> 7; k = rel & 127; v = We1[(k + 128) * 128 + n]; }
    else if (i < OFF_WE2T) { rel = i - OFF_W1E;  n = rel >> 6; k = rel & 63;  v = We1[(k + 256) * 128 + n]; }
    else if (i < OFF_WN1T) { rel = i - OFF_WE2T; n = rel >> 7; k = rel & 127; v = We2[k * 128 + n]; }
    else if (i < OFF_WN2T) { rel = i - OFF_WN1T; n = rel >> 8; k = rel & 255; v = Wn1[k * 128 + n]; }
    else if (i < OFF_WC1T) { rel = i - OFF_WN2T; n = rel >> 7; k = rel & 127; v = Wn2[k * 128 + n]; }
    else                   { rel = i - OFF_WC1T; n = rel >> 7; k = rel & 127; v = Wc1[k * 64 + n]; }
    wb[i] = f2bf(v);
}

// ---------------- ynode: Ys = nf @ We1_src, Yd = nf @ We1_dst (bf16 out) ----------------
__global__ __launch_bounds__(256, 4) void ynode_kernel(
    const float* __restrict__ nf, const short* __restrict__ wb,
    short* __restrict__ ysb, short* __restrict__ ydb)
{
    const int tid = threadIdx.x;
    const int wv = tid >> 6, lane = tid & 63, le = lane & 15, grp = lane >> 4;
    const int nb = blockIdx.x * 128, wbase = wv * 32;
    const int row0 = min(nb + wbase + le, NN - 1);
    const int row1 = min(nb + wbase + 16 + le, NN - 1);

    #pragma unroll 1
    for (int pass = 0; pass < 2; ++pass) {
        const short* wt = wb + (pass ? OFF_W1D : OFF_W1S);
        short* op = pass ? ydb : ysb;

        f32x4 acc[2][8];
        #pragma unroll
        for (int m = 0; m < 2; ++m)
            #pragma unroll
            for (int t = 0; t < 8; ++t) acc[m][t] = (f32x4){0.f, 0.f, 0.f, 0.f};

        #pragma unroll
        for (int kc = 0; kc < 4; ++kc) {
            const int gk = kc * 32 + grp * 8;
            const float* p0 = nf + (size_t)row0 * 128 + gk;
            const float* p1 = nf + (size_t)row1 * 128 + gk;
            const short8 a0 = cvt8(*(const float4*)p0, *(const float4*)(p0 + 4));
            const short8 a1 = cvt8(*(const float4*)p1, *(const float4*)(p1 + 4));
            short8 bfv[8];
            #pragma unroll
            for (int t = 0; t < 8; ++t)
                bfv[t] = *(const short8*)(wt + (size_t)(t * 16 + le) * 128 + gk);
            #pragma unroll
            for (int t = 0; t < 8; ++t) {
                acc[0][t] = __builtin_amdgcn_mfma_f32_16x16x32_bf16(a0, bfv[t], acc[0][t], 0, 0, 0);
                acc[1][t] = __builtin_amdgcn_mfma_f32_16x16x32_bf16(a1, bfv[t], acc[1][t], 0, 0, 0);
            }
        }
        #pragma unroll
        for (int t = 0; t < 8; ++t)
            #pragma unroll
            for (int m = 0; m < 2; ++m)
                #pragma unroll
                for (int r = 0; r < 4; ++r) {
                    const int row = nb + wbase + m * 16 + grp * 4 + r;
                    if (row < NN)
                        op[(size_t)row * 128 + t * 16 + le] = f2bf(acc[m][t][r]);
                }
    }
}

// ---------------- edge pipeline: register gathers + fp32 LDS h2-transpose ----------------
// 64 edges/block, 4 waves, 16 edges/wave. MLP1/MLP2 swapped with register
// Ys/Yd B-frag gathers + exch8 (zero-LDS, R9-proven). h2 goes through a
// per-wave fp32 LDS tile [16][136] ONLY to restore the quarter-wave
// contiguous atomic pattern (R3/R6/R8-proven, WRITE_SIZE 237 MB).
__global__ __launch_bounds__(256, 4) void edge_kernel(
    const short* __restrict__ ysb, const short* __restrict__ ydb,
    const float* __restrict__ ea, const float* __restrict__ coords,
    const int* __restrict__ ei, const short* __restrict__ wb,
    const float* __restrict__ be1, const float* __restrict__ be2,
    const float* __restrict__ bc1, const float* __restrict__ bc2,
    const float* __restrict__ Wc2f,
    float* __restrict__ aggr, float* __restrict__ coord_acc)
{
    __shared__ float Ht4[4][16 * 136];   // 8.5KB per wave, wave-private (no barriers)

    const int tid = threadIdx.x;
    const int wv = tid >> 6, lane = tid & 63, le = lane & 15, g = lane >> 4;
    const int e = (blockIdx.x * 4 + wv) * 16 + le;
    float* Ht = Ht4[wv];

    const int s0 = ei[e], d0 = ei[NE + e];

    // register gathers: Ys[s0], Yd[d0] as B-frag chunks (cc=0..3), 16B per load
    short8 ys8[4], yd8[4];
    #pragma unroll
    for (int cc = 0; cc < 4; ++cc) {
        ys8[cc] = *(const short8*)(ysb + (size_t)s0 * 128 + cc * 32 + g * 8);
        yd8[cc] = *(const short8*)(ydb + (size_t)d0 * 128 + cc * 32 + g * 8);
    }

    // edge_attr B-frags (fp32 stream)
    short8 eaB[2];
    #pragma unroll
    for (int kc = 0; kc < 2; ++kc) {
        const float* pe = ea + (size_t)e * 64 + kc * 32 + g * 8;
        eaB[kc] = cvt8(*(const float4*)pe, *(const float4*)(pe + 4));
    }

    // ===== MLP1 ea-part (swapped): C lane le = edge, col t*16+g*4+r
    f32x4 acc[8];
    #pragma unroll
    for (int t = 0; t < 8; ++t) acc[t] = (f32x4){0.f, 0.f, 0.f, 0.f};

    const short* w1e = wb + OFF_W1E;
    #pragma unroll
    for (int kc = 0; kc < 2; ++kc) {
        const int gk = kc * 32 + g * 8;
        short8 wfv[8];
        #pragma unroll
        for (int t = 0; t < 8; ++t)
            wfv[t] = *(const short8*)(w1e + (size_t)(t * 16 + le) * 64 + gk);
        #pragma unroll
        for (int t = 0; t < 8; ++t)
            acc[t] = __builtin_amdgcn_mfma_f32_16x16x32_bf16(wfv[t], eaB[kc], acc[t], 0, 0, 0);
    }

    // pack ea-part C-frags to bf16 pairs
    uint32_t hp[8][2];
    #pragma unroll
    for (int t = 0; t < 8; ++t) {
        hp[t][0] = pk2(acc[t][0], acc[t][1]);
        hp[t][1] = pk2(acc[t][2], acc[t][3]);
    }

    // ===== h1 B-frags: exch(ea-part) + Ys + Yd + be1, silu — all in registers
    short8 h1f[4];
    #pragma unroll
    for (int cc = 0; cc < 4; ++cc) {
        const short8 ex = exch8(hp[cc*2][0], hp[cc*2][1], hp[cc*2+1][0], hp[cc*2+1][1], g, le);
        const float* bp = be1 + cc * 32 + g * 8;
        #pragma unroll
        for (int j = 0; j < 8; ++j)
            h1f[cc][j] = f2bf(silu_f(bf2f(ex[j]) + bf2f(ys8[cc][j]) + bf2f(yd8[cc][j]) + bp[j]));
    }

    // ===== MLP2 (swapped): acc2[t], K=128
    f32x4 acc2[8];
    #pragma unroll
    for (int t = 0; t < 8; ++t) acc2[t] = (f32x4){0.f, 0.f, 0.f, 0.f};

    const short* w2 = wb + OFF_WE2T;
    #pragma unroll
    for (int cc = 0; cc < 4; ++cc) {
        const int gk = cc * 32 + g * 8;
        short8 wfv[8];
        #pragma unroll
        for (int t = 0; t < 8; ++t)
            wfv[t] = *(const short8*)(w2 + (size_t)(t * 16 + le) * 128 + gk);
        #pragma unroll
        for (int t = 0; t < 8; ++t)
            acc2[t] = __builtin_amdgcn_mfma_f32_16x16x32_bf16(wfv[t], h1f[cc], acc2[t], 0, 0, 0);
    }

    // ===== h2 epilogue: fp32 -> LDS tile [edge][col] (wave-private, race-free)
    #pragma unroll
    for (int t = 0; t < 8; ++t) {
        #pragma unroll
        for (int r = 0; r < 4; ++r) {
            const int col = t * 16 + g * 4 + r;
            Ht[le * 136 + col] = silu_f(acc2[t][r] + be2[col]);
        }
    }

    // quarter-wave contiguous atomic scatter (proven pattern: 16 lanes -> one
    // 64B row segment per instruction). t-order rotated by g to spread banks.
    #pragma unroll
    for (int r = 0; r < 4; ++r) {
        const int er = g * 4 + r;
        const int dr = __shfl(d0, er);
        const float* hrow = &Ht[er * 136];
        #pragma unroll
        for (int t = 0; t < 8; ++t) {
            const int t2 = (t + g) & 7;
            atomicAdd(&aggr[(size_t)dr * 128 + t2 * 16 + le], hrow[t2 * 16 + le]);
        }
    }

    // h2 B-frags for coord MLP from the fp32 tile
    short8 h2f[4];
    #pragma unroll
    for (int cc = 0; cc < 4; ++cc) {
        const float* hq = &Ht[le * 136 + cc * 32 + g * 8];
        h2f[cc] = cvt8(*(const float4*)hq, *(const float4*)(hq + 4));
    }

    // ===== coord MLP (swapped), N=64: acc3[t=0..3]
    f32x4 acc3[4];
    #pragma unroll
    for (int t = 0; t < 4; ++t) acc3[t] = (f32x4){0.f, 0.f, 0.f, 0.f};

    const short* wc = wb + OFF_WC1T;
    #pragma unroll
    for (int cc = 0; cc < 4; ++cc) {
        const int gk = cc * 32 + g * 8;
        short8 wfv[4];
        #pragma unroll
        for (int t = 0; t < 4; ++t)
            wfv[t] = *(const short8*)(wc + (size_t)(t * 16 + le) * 128 + gk);
        #pragma unroll
        for (int t = 0; t < 4; ++t)
            acc3[t] = __builtin_amdgcn_mfma_f32_16x16x32_bf16(wfv[t], h2f[cc], acc3[t], 0, 0, 0);
    }

    // coord_w: per-lane partial over cols, reduce across the 4 g-lanes of this edge
    float part = 0.f;
    #pragma unroll
    for (int t = 0; t < 4; ++t)
        #pragma unroll
        for (int r = 0; r < 4; ++r) {
            const int col = t * 16 + g * 4 + r;
            part += silu_f(acc3[t][r] + bc1[col]) * Wc2f[col];
        }
    part += __shfl_xor(part, 16);
    part += __shfl_xor(part, 32);

    if (g == 0) {
        const float wq = part + bc2[0];
        const float dx = coords[3 * s0 + 0] - coords[3 * d0 + 0];
        const float dy = coords[3 * s0 + 1] - coords[3 * d0 + 1];
        const float dz = coords[3 * s0 + 2] - coords[3 * d0 + 2];
        const float inv = wq / (sqrtf(dx * dx + dy * dy + dz * dz) + 1e-8f);
        atomicAdd(&coord_acc[3 * d0 + 0], dx * inv);
        atomicAdd(&coord_acc[3 * d0 + 1], dy * inv);
        atomicAdd(&coord_acc[3 * d0 + 2], dz * inv);
    }
}

// ---------------- node update (MFMA, barrier-free, fp32 inputs) ----------------
__global__ __launch_bounds__(256, 2) void node_kernel(
    const float* __restrict__ nf, const float* __restrict__ coords,
    const short* __restrict__ wb,
    const float* __restrict__ bn1, const float* __restrict__ bn2,
    const float* __restrict__ aggr, const float* __restrict__ coord_acc,
    float* __restrict__ out)
{
    __shared__ short Hs[128][136];

    const int tid = threadIdx.x;
    const int wv = tid >> 6, lane = tid & 63, le = lane & 15, grp = lane >> 4;
    const int nb = blockIdx.x * 128, wbase = wv * 32;
    const int row0 = min(nb + wbase + le, NN - 1);
    const int row1 = min(nb + wbase + 16 + le, NN - 1);

    // MLP1: K=256 ([nf | aggr])
    f32x4 acc[2][8];
    #pragma unroll
    for (int m = 0; m < 2; ++m)
        #pragma unroll
        for (int t = 0; t < 8; ++t) acc[m][t] = (f32x4){0.f, 0.f, 0.f, 0.f};

    const short* w1 = wb + OFF_WN1T;
    #pragma unroll
    for (int kc = 0; kc < 8; ++kc) {
        const int gk = kc * 32 + grp * 8;
        const float* p0 = (kc < 4) ? nf + (size_t)row0 * 128 + gk : aggr + (size_t)row0 * 128 + gk - 128;
        const float* p1 = (kc < 4) ? nf + (size_t)row1 * 128 + gk : aggr + (size_t)row1 * 128 + gk - 128;
        const short8 a0 = cvt8(*(const float4*)p0, *(const float4*)(p0 + 4));
        const short8 a1 = cvt8(*(const float4*)p1, *(const float4*)(p1 + 4));
        short8 bfv[8];
        #pragma unroll
        for (int t = 0; t < 8; ++t)
            bfv[t] = *(const short8*)(w1 + (size_t)(t * 16 + le) * 256 + gk);
        #pragma unroll
        for (int t = 0; t < 8; ++t) {
            acc[0][t] = __builtin_amdgcn_mfma_f32_16x16x32_bf16(a0, bfv[t], acc[0][t], 0, 0, 0);
            acc[1][t] = __builtin_amdgcn_mfma_f32_16x16x32_bf16(a1, bfv[t], acc[1][t], 0, 0, 0);
        }
    }
    #pragma unroll
    for (int t = 0; t < 8; ++t) {
        const float b1 = bn1[t * 16 + le];
        #pragma unroll
        for (int m = 0; m < 2; ++m)
            #pragma unroll
            for (int r = 0; r < 4; ++r)
                Hs[wbase + m * 16 + grp * 4 + r][t * 16 + le] = f2bf(silu_f(acc[m][t][r] + b1));
    }

    // MLP2: K=128, then residual
    f32x4 acc2[2][8];
    #pragma unroll
    for (int m = 0; m < 2; ++m)
        #pragma unroll
        for (int t = 0; t < 8; ++t) acc2[m][t] = (f32x4){0.f, 0.f, 0.f, 0.f};

    const short* w2 = wb + OFF_WN2T;
    #pragma unroll
    for (int kc = 0; kc < 4; ++kc) {
        const int gk = kc * 32 + grp * 8;
        const short8 a0 = *(const short8*)&Hs[wbase + le][gk];
        const short8 a1 = *(const short8*)&Hs[wbase + 16 + le][gk];
        short8 bfv[8];
        #pragma unroll
        for (int t = 0; t < 8; ++t)
            bfv[t] = *(const short8*)(w2 + (size_t)(t * 16 + le) * 128 + gk);
        #pragma unroll
        for (int t = 0; t < 8; ++t) {
            acc2[0][t] = __builtin_amdgcn_mfma_f32_16x16x32_bf16(a0, bfv[t], acc2[0][t], 0, 0, 0);
            acc2[1][t] = __builtin_amdgcn_mfma_f32_16x16x32_bf16(a1, bfv[t], acc2[1][t], 0, 0, 0);
        }
    }
    #pragma unroll
    for (int t = 0; t < 8; ++t) {
        const float b2 = bn2[t * 16 + le];
        #pragma unroll
        for (int m = 0; m < 2; ++m)
            #pragma unroll
            for (int r = 0; r < 4; ++r) {
                const int row = nb + wbase + m * 16 + grp * 4 + r;
                if (row < NN) {
                    const int c = t * 16 + le;
                    out[(size_t)row * 128 + c] = acc2[m][t][r] + b2 + nf[(size_t)row * 128 + c];
                }
            }
    }

    // coords epilogue
    for (int i = tid; i < 384; i += 256) {
        const int n = nb + i / 3, j = i % 3;
        if (n < NN)
            out[(size_t)NN * 128 + 3 * n + j] = coords[3 * n + j] + coord_acc[3 * n + j];
    }
}

extern "C" void kernel_launch(void* const* d_in, const int* in_sizes, int n_in,
                              void* d_out, int out_size, void* d_ws, size_t ws_size,
                              hipStream_t stream)
{
    const float* node_feat  = (const float*)d_in[0];
    const float* edge_attr  = (const float*)d_in[1];
    const float* coords     = (const float*)d_in[2];
    const int*   edge_index = (const int*)d_in[3];
    const float* We1 = (const float*)d_in[4];
    const float* be1 = (const float*)d_in[5];
    const float* We2 = (const float*)d_in[6];
    const float* be2 = (const float*)d_in[7];
    const float* Wn1 = (const float*)d_in[8];
    const float* bn1 = (const float*)d_in[9];
    const float* Wn2 = (const float*)d_in[10];
    const float* bn2 = (const float*)d_in[11];
    const float* Wc1 = (const float*)d_in[12];
    const float* bc1 = (const float*)d_in[13];
    const float* Wc2 = (const float*)d_in[14];
    const float* bc2 = (const float*)d_in[15];
    float* out = (float*)d_out;

    const size_t sz_wb  = (size_t)W_TOTAL * 2;      // 229 KB
    const size_t sz_agg = (size_t)NN * 128 * 4;     // 25.6 MB
    const size_t sz_cac = (size_t)NN * 3 * 4;       // 600 KB
    const size_t sz_y   = (size_t)NN * 128 * 2;     // 12.8 MB each

    char* p = (char*)d_ws;
    short* wbf       = (short*)p;  p += sz_wb;
    float* aggr      = (float*)p;  p += sz_agg;
    float* coord_acc = (float*)p;  p += sz_cac;
    short* ysb       = (short*)p;  p += sz_y;
    short* ydb       = (short*)p;
    (void)ws_size;

    const int n4 = (NN * 128 + NN * 3) / 4;
    const int eg = NE / 64;                   // 6250 blocks (4 waves x 16 edges)
    const int ng = (NN + 127) / 128;          // 391

    prep_kernel<<<(W_TOTAL + 255) / 256, 256, 0, stream>>>(We1, We2, Wn1, Wn2, Wc1, wbf);
    zero_kernel<<<2048, 256, 0, stream>>>((float4*)aggr, n4);
    ynode_kernel<<<ng, 256, 0, stream>>>(node_feat, wbf, ysb, ydb);

    edge_kernel<<<eg, 256, 0, stream>>>(
        ysb, ydb, edge_attr, coords, edge_index, wbf,
        be1, be2, bc1, bc2, Wc2, aggr, coord_acc);

    node_kernel<<<ng, 256, 0, stream>>>(
        node_feat, coords, wbf, bn1, bn2, aggr, coord_acc, out);
}